// Round 1
// baseline (11.440 us; speedup 1.0000x reference)
//
#include <hip/hip_runtime.h>
#include <hip/hip_bf16.h>

// loss = -(1/B) * sum_{b,t} [t < lengths[b]] * (gt[b,t]==0 ? 1 : 2) * log(scores[b,t,gt[b,t]])
//
// Key observation: only B*T = 12032 scalar scores are ever read (a gather),
// not the full [B,T,V] = 1.54 GB tensor. So the kernel is a sparse gather +
// small deterministic reduction.

#define BETA 2.0f

__global__ void loss_partial_kernel(const float* __restrict__ scores,
                                    const int* __restrict__ gt,
                                    const int* __restrict__ lengths,
                                    float* __restrict__ partials,
                                    int BT, int T, int V) {
    int idx = blockIdx.x * blockDim.x + threadIdx.x;   // element index in [0, B*T)
    float val = 0.0f;
    if (idx < BT) {
        int b = idx / T;
        int t = idx - b * T;
        if (t < lengths[b]) {
            int g = gt[idx];
            float s = scores[(size_t)idx * (size_t)V + (size_t)g];
            float w = (g == 0) ? 1.0f : BETA;
            val = w * logf(s);
        }
    }
    // wave (64-lane) reduction
    #pragma unroll
    for (int off = 32; off > 0; off >>= 1)
        val += __shfl_down(val, off, 64);

    __shared__ float sm[2];   // 128 threads = 2 waves
    int lane = threadIdx.x & 63;
    int wid  = threadIdx.x >> 6;
    if (lane == 0) sm[wid] = val;
    __syncthreads();
    if (threadIdx.x == 0) partials[blockIdx.x] = sm[0] + sm[1];
}

__global__ void loss_final_kernel(const float* __restrict__ partials,
                                  float* __restrict__ out,
                                  int n, float invB) {
    float val = 0.0f;
    for (int i = threadIdx.x; i < n; i += 64)
        val += partials[i];
    #pragma unroll
    for (int off = 32; off > 0; off >>= 1)
        val += __shfl_down(val, off, 64);
    if (threadIdx.x == 0)
        out[0] = -val * invB;
}

extern "C" void kernel_launch(void* const* d_in, const int* in_sizes, int n_in,
                              void* d_out, int out_size, void* d_ws, size_t ws_size,
                              hipStream_t stream) {
    const float* scores  = (const float*)d_in[0];   // [B,T,V] float32
    const int*   gt      = (const int*)d_in[1];     // [B,T]  (int64 in ref -> int32 here)
    const int*   lengths = (const int*)d_in[2];     // [B]
    float* out = (float*)d_out;                     // [1] float32
    float* ws  = (float*)d_ws;                      // per-block partials

    int BT = in_sizes[1];                 // B*T = 12032
    int B  = in_sizes[2];                 // 64
    int T  = BT / B;                      // 188
    int V  = (int)((long long)in_sizes[0] / (long long)BT);  // 32000

    const int BLOCK = 128;
    int blocks = (BT + BLOCK - 1) / BLOCK;   // 94

    loss_partial_kernel<<<blocks, BLOCK, 0, stream>>>(scores, gt, lengths, ws, BT, T, V);
    loss_final_kernel<<<1, 64, 0, stream>>>(ws, out, blocks, 1.0f / (float)B);
}